// Round 6
// baseline (947.982 us; speedup 1.0000x reference)
//
#include <hip/hip_runtime.h>
#include <cstdint>
#include <math.h>

#define T_SEQ 2048
#define BATCH 2
#define NH 16
#define NKV 4
#define HD 128

typedef __attribute__((ext_vector_type(8))) short short8;
typedef __attribute__((ext_vector_type(4))) float f32x4;

__device__ __forceinline__ ushort f2bf(float f) {
  uint32_t u = __builtin_bit_cast(uint32_t, f);
  u += 0x7FFF + ((u >> 16) & 1);  // RNE
  return (ushort)(u >> 16);
}
__device__ __forceinline__ ushort f2bf_trunc(float f) {
  return (ushort)(__builtin_bit_cast(uint32_t, f) >> 16);
}
__device__ __forceinline__ float bf2f(ushort u) {
  uint32_t v = ((uint32_t)u) << 16;
  return __builtin_bit_cast(float, v);
}
// async 16B/lane global->LDS DMA. lds must be wave-uniform; hw adds lane*16.
__device__ __forceinline__ void ld16(void* lds, const void* g) {
  __builtin_amdgcn_global_load_lds((const __attribute__((address_space(1))) void*)g,
                                   (__attribute__((address_space(3))) void*)lds,
                                   16, 0, 0);
}

// ---------------------------------------------------------------------------
// Fused prep: x f32->bf16 convert + 4 weight transposes (f32 [K][N] -> bf16
// [N][K]). One launch instead of five.
// Regions by blockIdx.x: [0,8192) x-convert; then Wq 4096, Wk 1024, Wv 1024,
// Wo 4096 transpose blocks (32x32 tiles).
// ---------------------------------------------------------------------------
__global__ __launch_bounds__(256) void prep(
    const float* __restrict__ x, ushort* __restrict__ xb,
    const float* __restrict__ Wq, const float* __restrict__ Wk,
    const float* __restrict__ Wv, const float* __restrict__ Wo,
    ushort* __restrict__ wqkvT, ushort* __restrict__ woT) {
  __shared__ float tile[32][33];
  const int bid = blockIdx.x;
  const int tid = threadIdx.x;
  if (bid < 8192) {  // x convert: 4096*2048 elems, 4/thread
    int i = (bid * 256 + tid) * 4;
    float4 v = *(const float4*)&x[i];
    ushort4 o;
    o.x = f2bf(v.x); o.y = f2bf(v.y); o.z = f2bf(v.z); o.w = f2bf(v.w);
    *(ushort4*)&xb[i] = o;
    return;
  }
  const float* in;
  ushort* out;
  int N, lid;
  if (bid < 12288)      { in = Wq; out = wqkvT;                        N = 2048; lid = bid - 8192; }
  else if (bid < 13312) { in = Wk; out = wqkvT + (size_t)2048 * 2048;  N = 512;  lid = bid - 12288; }
  else if (bid < 14336) { in = Wv; out = wqkvT + (size_t)2560 * 2048;  N = 512;  lid = bid - 13312; }
  else                  { in = Wo; out = woT;                          N = 2048; lid = bid - 14336; }
  const int K = 2048;
  const int nb = N / 32;
  const int n0 = (lid % nb) * 32, k0 = (lid / nb) * 32;
  const int r = tid >> 3, c4 = (tid & 7) << 2;
  float4 v = *(const float4*)&in[(size_t)(k0 + r) * N + n0 + c4];
  tile[r][c4 + 0] = v.x; tile[r][c4 + 1] = v.y;
  tile[r][c4 + 2] = v.z; tile[r][c4 + 3] = v.w;
  __syncthreads();
  ushort4 o;
  o.x = f2bf(tile[c4 + 0][r]); o.y = f2bf(tile[c4 + 1][r]);
  o.z = f2bf(tile[c4 + 2][r]); o.w = f2bf(tile[c4 + 3][r]);
  *(ushort4*)&out[(size_t)(n0 + r) * K + k0 + c4] = o;
}

// ---------------------------------------------------------------------------
// bf16 GEMM C[M,N] = A[M,K] * Bt[N,K]^T. 128x128 tile, BK=32, 4 waves (2x2),
// global_load_lds staging, XOR-swizzled LDS.
// MODE 0: float C (output projection).
// MODE 1: qkv mode — cols [0,2048) plain bf16 -> Cq; cols [2048,2560) K-RoPE
//         then bf16 -> Cq; cols [2560,3072) transposed bf16 -> vTo[d][row].
// ---------------------------------------------------------------------------
template <int MODE>
__global__ __launch_bounds__(256) void gemm_bt(const ushort* __restrict__ A,
                                               const ushort* __restrict__ Bt,
                                               float* __restrict__ Cf,
                                               ushort* __restrict__ Cq,
                                               ushort* __restrict__ vTo,
                                               int M, int N, int K) {
  __shared__ __align__(16) ushort As[128 * 32];
  __shared__ __align__(16) ushort Bs[128 * 32];
  const int tid = threadIdx.x;
  const int w = tid >> 6, l = tid & 63;
  const int wr = w >> 1, wc = w & 1;
  const int quad = l >> 4, l15 = l & 15;
  const int bm = blockIdx.y * 128, bn = blockIdx.x * 128;

  f32x4 acc[4][4];
#pragma unroll
  for (int mi = 0; mi < 4; ++mi)
#pragma unroll
    for (int ni = 0; ni < 4; ++ni)
#pragma unroll
      for (int r = 0; r < 4; ++r) acc[mi][ni][r] = 0.f;

  for (int k0 = 0; k0 < K; k0 += 32) {
    __syncthreads();
#pragma unroll
    for (int j = 0; j < 2; ++j) {
      int r0 = w * 32 + j * 16;
      int row = r0 + (l >> 2);
      int gc = (l & 3) ^ ((row >> 1) & 3);
      ld16(&As[r0 * 32], &A[(size_t)(bm + row) * K + k0 + gc * 8]);
      ld16(&Bs[r0 * 32], &Bt[(size_t)(bn + row) * K + k0 + gc * 8]);
    }
    __syncthreads();
    short8 af[4], bf[4];
#pragma unroll
    for (int mi = 0; mi < 4; ++mi) {
      int m = wr * 64 + mi * 16 + l15;
      af[mi] = *(const short8*)&As[m * 32 + (quad ^ ((m >> 1) & 3)) * 8];
    }
#pragma unroll
    for (int ni = 0; ni < 4; ++ni) {
      int n = wc * 64 + ni * 16 + l15;
      bf[ni] = *(const short8*)&Bs[n * 32 + (quad ^ ((n >> 1) & 3)) * 8];
    }
#pragma unroll
    for (int mi = 0; mi < 4; ++mi)
#pragma unroll
      for (int ni = 0; ni < 4; ++ni)
        acc[mi][ni] = __builtin_amdgcn_mfma_f32_16x16x32_bf16(af[mi], bf[ni], acc[mi][ni], 0, 0, 0);
  }
  // epilogue: C/D layout col=lane&15, row=quad*4+reg
  if constexpr (MODE == 0) {
#pragma unroll
    for (int mi = 0; mi < 4; ++mi)
#pragma unroll
      for (int ni = 0; ni < 4; ++ni)
#pragma unroll
        for (int r = 0; r < 4; ++r) {
          int grow = bm + wr * 64 + mi * 16 + quad * 4 + r;
          int gcol = bn + wc * 64 + ni * 16 + l15;
          Cf[(size_t)grow * N + gcol] = acc[mi][ni][r];
        }
  } else {
    const int sec = bn >> 7;  // 128-col section id, uniform per block
    if (sec < 16) {           // Q region: plain bf16
#pragma unroll
      for (int mi = 0; mi < 4; ++mi)
#pragma unroll
        for (int ni = 0; ni < 4; ++ni)
#pragma unroll
          for (int r = 0; r < 4; ++r) {
            int grow = bm + wr * 64 + mi * 16 + quad * 4 + r;
            int gcol = bn + wc * 64 + ni * 16 + l15;
            Cq[(size_t)grow * 3072 + gcol] = f2bf(acc[mi][ni][r]);
          }
    } else if (sec < 20) {    // K region: fused interleaved RoPE
#pragma unroll
      for (int mi = 0; mi < 4; ++mi)
#pragma unroll
        for (int ni = 0; ni < 4; ++ni) {
          int gcol = bn + wc * 64 + ni * 16 + l15;
          int pos = gcol & 127;          // position within head dim
          float inv = expf((float)(pos >> 1) * -0.14391156831212788f);
#pragma unroll
          for (int r = 0; r < 4; ++r) {
            float val = acc[mi][ni][r];
            float part = __shfl_xor(val, 1);  // partner element (gcol^1)
            int grow = bm + wr * 64 + mi * 16 + quad * 4 + r;
            float sn, cs;
            sincosf((float)(grow & (T_SEQ - 1)) * inv, &sn, &cs);
            float o = (pos & 1) ? (part * sn + val * cs) : (val * cs - part * sn);
            Cq[(size_t)grow * 3072 + gcol] = f2bf(o);
          }
        }
    } else {                  // V region: transposed write to vT[d][row]
#pragma unroll
      for (int mi = 0; mi < 4; ++mi)
#pragma unroll
        for (int ni = 0; ni < 4; ++ni) {
          int d = bn - 2560 + wc * 64 + ni * 16 + l15;
          int grow0 = bm + wr * 64 + mi * 16 + quad * 4;
          ushort4 o4;
          o4.x = f2bf(acc[mi][ni][0]);
          o4.y = f2bf(acc[mi][ni][1]);
          o4.z = f2bf(acc[mi][ni][2]);
          o4.w = f2bf(acc[mi][ni][3]);
          *(ushort4*)&vTo[(size_t)d * 4096 + grow0] = o4;
        }
    }
  }
}

// ---------------------------------------------------------------------------
// MFMA flash attention v5. grid (32, NKV, B), 512 thr = 8 waves.
// Block covers 4 q-heads (one KV group) x 32 q-rows, sharing K/V staging.
// Wave w: head (w>>1), rows (w&1)*16..+16. Each block processes TWO
// complementary q-tiles (63-bx, bx) -> exactly 33 k-iters per block: perfectly
// balanced 256-block grid (1/CU).
// SC (scale*log2e) folded into Q fragments; P converts truncate; no-max
// softmax with epilogue-only butterfly reduce. Double-buffered K/V.
// LDS 80KB: Ks[2]/Vt[2] 64KB + Ps 8x2KB.
// ---------------------------------------------------------------------------
__global__ __launch_bounds__(512, 2) void attn_mfma(const ushort* __restrict__ qkv,
                                                    const ushort* __restrict__ vT,
                                                    ushort* __restrict__ ao) {
  __shared__ __align__(16) ushort Ks[2][64 * 128];
  __shared__ __align__(16) ushort Vt[2][128 * 64];
  __shared__ __align__(16) ushort Ps[8][16 * 64];
  const int tid = threadIdx.x;
  const int w = tid >> 6, l = tid & 63;
  const int quad = l >> 4, l15 = l & 15;
  const int hw = w >> 1, sub = w & 1;
  const int kvh = blockIdx.y, b = blockIdx.z;
  const int h = kvh * 4 + hw;
  const size_t krow0 = (size_t)b * T_SEQ;
  const float SC = 0.12751744595764253f;  // (1/sqrt(128)) * log2(e)

  ushort* pw = Ps[w];
  const int within = l & 7;
  const int colbase = l15 >> 3;  // 0 or 1

  // K/V staging into buffer bufi (swizzles match the fragment reads below)
  auto stage = [&](int kt, int bufi) {
    const int kt0 = kt << 6;
    ushort* kb = Ks[bufi];
    ushort* vb = Vt[bufi];
#pragma unroll
    for (int j = 0; j < 2; ++j) {  // K tile 64x128
      int r0 = w * 8 + j * 4;
      int row = r0 + (l >> 4);
      int gc = (l & 15) ^ ((row >> 1) & 7);
      ld16(&kb[r0 * 128], &qkv[(krow0 + kt0 + row) * 3072 + 2048 + kvh * 128 + gc * 8]);
    }
#pragma unroll
    for (int j = 0; j < 2; ++j) {  // V^T tile 128x64
      int r0 = w * 16 + j * 8;
      int row = r0 + (l >> 3);
      int gc = (l & 7) ^ (row & 7);
      ld16(&vb[r0 * 64], &vT[(size_t)(kvh * 128 + row) * 4096 + krow0 + kt0 + gc * 8]);
    }
  };

#pragma unroll 1
  for (int ph = 0; ph < 2; ++ph) {
    const int qt = ph ? (int)blockIdx.x : 63 - (int)blockIdx.x;
    const int qt0 = qt << 5;
    const size_t qrow0 = krow0 + qt0;

    // Q fragments in registers; RoPE + SC folded in.
    const int t_pos = qt0 + sub * 16 + l15;
    short8 qf[4];
#pragma unroll
    for (int kc = 0; kc < 4; ++kc) {
      short8 raw = *(const short8*)&qkv[(qrow0 + sub * 16 + l15) * 3072 + h * 128 + kc * 32 + quad * 8];
#pragma unroll
      for (int u = 0; u < 4; ++u) {
        int i_idx = kc * 16 + quad * 4 + u;
        float inv = expf((float)i_idx * -0.14391156831212788f);  // ln(10000)/64
        float sn, cs;
        sincosf((float)t_pos * inv, &sn, &cs);
        cs *= SC; sn *= SC;
        float x1 = bf2f((ushort)raw[2 * u]);
        float x2 = bf2f((ushort)raw[2 * u + 1]);
        qf[kc][2 * u]     = (short)f2bf(x1 * cs - x2 * sn);
        qf[kc][2 * u + 1] = (short)f2bf(x1 * sn + x2 * cs);
      }
    }

    f32x4 oacc[8];
#pragma unroll
    for (int i = 0; i < 8; ++i)
#pragma unroll
      for (int r = 0; r < 4; ++r) oacc[i][r] = 0.f;
    float lpart[4] = {0.f, 0.f, 0.f, 0.f};

    const int nkt = (qt >> 1) + 1;
    __syncthreads();  // prior phase's LDS reads complete before re-priming
    stage(0, 0);
    for (int kt = 0; kt < nkt; ++kt) {
      __syncthreads();  // (vmcnt drain) stage(kt) landed; prior buffer free
      if (kt + 1 < nkt) stage(kt + 1, (kt + 1) & 1);
      const ushort* kb = Ks[kt & 1];
      const ushort* vb = Vt[kt & 1];

      // S = Q K^T (wave rows sub*16.., cols 0..63); already scaled by SC
      f32x4 sacc[4];
#pragma unroll
      for (int ni = 0; ni < 4; ++ni)
#pragma unroll
        for (int r = 0; r < 4; ++r) sacc[ni][r] = 0.f;
#pragma unroll
      for (int kc = 0; kc < 4; ++kc) {
#pragma unroll
        for (int ni = 0; ni < 4; ++ni) {
          int n = ni * 16 + l15;
          short8 bfr = *(const short8*)&kb[n * 128 + ((kc * 4 + quad) ^ ((n >> 1) & 7)) * 8];
          sacc[ni] = __builtin_amdgcn_mfma_f32_16x16x32_bf16(qf[kc], bfr, sacc[ni], 0, 0, 0);
        }
      }

      // p = exp2(s); stream to LDS (truncated bf16); accumulate partial l.
      const int kt0 = kt << 6;
      if (kt == nkt - 1) {  // diagonal tile: causal mask
        const int rowg = qt0 + sub * 16 + quad * 4;
#pragma unroll
        for (int ni = 0; ni < 4; ++ni) {
          const int colid = kt0 + ni * 16 + l15;
#pragma unroll
          for (int r = 0; r < 4; ++r) {
            float s = (colid > rowg + r) ? -1e30f : sacc[ni][r];
            float pv = __builtin_amdgcn_exp2f(s);
            lpart[r] += pv;
            int prow = quad * 4 + r;
            pw[prow * 64 + (((ni * 2 + colbase) ^ (prow & 7)) << 3) + within] = f2bf_trunc(pv);
          }
        }
      } else {
#pragma unroll
        for (int ni = 0; ni < 4; ++ni)
#pragma unroll
          for (int r = 0; r < 4; ++r) {
            float pv = __builtin_amdgcn_exp2f(sacc[ni][r]);
            lpart[r] += pv;
            int prow = quad * 4 + r;
            pw[prow * 64 + (((ni * 2 + colbase) ^ (prow & 7)) << 3) + within] = f2bf_trunc(pv);
          }
      }

      // O += P V  (A = Ps rows m=l&15, B = Vt rows d)
#pragma unroll
      for (int kc = 0; kc < 2; ++kc) {
        short8 a = *(const short8*)&pw[l15 * 64 + ((kc * 4 + quad) ^ (l15 & 7)) * 8];
#pragma unroll
        for (int ni2 = 0; ni2 < 8; ++ni2) {
          int d = ni2 * 16 + l15;
          short8 bfr = *(const short8*)&vb[d * 64 + ((kc * 4 + quad) ^ (d & 7)) * 8];
          oacc[ni2] = __builtin_amdgcn_mfma_f32_16x16x32_bf16(a, bfr, oacc[ni2], 0, 0, 0);
        }
      }
    }

    // phase epilogue: one butterfly reduce of l per row, normalize + store
#pragma unroll
    for (int r = 0; r < 4; ++r) {
      float lv = lpart[r];
      lv += __shfl_xor(lv, 1);
      lv += __shfl_xor(lv, 2);
      lv += __shfl_xor(lv, 4);
      lv += __shfl_xor(lv, 8);
      float inv = 1.f / lv;
      size_t grow = qrow0 + sub * 16 + quad * 4 + r;
#pragma unroll
      for (int ni2 = 0; ni2 < 8; ++ni2)
        ao[grow * 2048 + h * 128 + ni2 * 16 + l15] = f2bf(oacc[ni2][r] * inv);
    }
  }
}

// ---------------------------------------------------------------------------
extern "C" void kernel_launch(void* const* d_in, const int* in_sizes, int n_in,
                              void* d_out, int out_size, void* d_ws, size_t ws_size,
                              hipStream_t stream) {
  const float* x  = (const float*)d_in[0];
  const float* Wq = (const float*)d_in[1];
  const float* Wk = (const float*)d_in[2];
  const float* Wv = (const float*)d_in[3];
  const float* Wo = (const float*)d_in[4];
  float* y = (float*)d_out;

  const int M = BATCH * T_SEQ;  // 4096
  ushort* xb    = (ushort*)d_ws;                    // 4096*2048  (16 MB)
  ushort* wqkvT = xb + (size_t)M * 2048;            // 3072*2048  (12 MB)
  ushort* woT   = wqkvT + (size_t)3072 * 2048;      // 2048*2048  ( 8 MB)
  ushort* qkv   = woT + (size_t)2048 * 2048;        // 4096*3072  (24 MB; v-sec unused)
  ushort* vTb   = qkv + (size_t)M * 3072;           // 512*4096   ( 4 MB)
  ushort* aob   = vTb + (size_t)512 * 4096;         // 4096*2048  (16 MB)

  prep<<<18432, 256, 0, stream>>>(x, xb, Wq, Wk, Wv, Wo, wqkvT, woT);

  gemm_bt<1><<<dim3(3072 / 128, M / 128), 256, 0, stream>>>(
      xb, wqkvT, nullptr, qkv, vTb, M, 3072, 2048);

  attn_mfma<<<dim3(32, NKV, BATCH), 512, 0, stream>>>(qkv, vTb, aob);

  gemm_bt<0><<<dim3(2048 / 128, M / 128), 256, 0, stream>>>(
      aob, woT, y, nullptr, nullptr, M, 2048, 2048);
}

// Round 7
// 316.023 us; speedup vs baseline: 2.9997x; 2.9997x over previous
//
#include <hip/hip_runtime.h>
#include <cstdint>
#include <math.h>

#define T_SEQ 2048
#define BATCH 2
#define NH 16
#define NKV 4
#define HD 128

typedef __attribute__((ext_vector_type(8))) short short8;
typedef __attribute__((ext_vector_type(4))) float f32x4;

__device__ __forceinline__ ushort f2bf(float f) {
  uint32_t u = __builtin_bit_cast(uint32_t, f);
  u += 0x7FFF + ((u >> 16) & 1);  // RNE
  return (ushort)(u >> 16);
}
__device__ __forceinline__ ushort f2bf_trunc(float f) {
  return (ushort)(__builtin_bit_cast(uint32_t, f) >> 16);
}
__device__ __forceinline__ float bf2f(ushort u) {
  uint32_t v = ((uint32_t)u) << 16;
  return __builtin_bit_cast(float, v);
}
// async 16B/lane global->LDS DMA. lds must be wave-uniform; hw adds lane*16.
__device__ __forceinline__ void ld16(void* lds, const void* g) {
  __builtin_amdgcn_global_load_lds((const __attribute__((address_space(1))) void*)g,
                                   (__attribute__((address_space(3))) void*)lds,
                                   16, 0, 0);
}

// ---------------------------------------------------------------------------
// Fused prep: x f32->bf16 convert + 4 weight transposes (f32 [K][N] -> bf16
// [N][K]). Regions by blockIdx.x: [0,8192) x-convert; then Wq 4096, Wk 1024,
// Wv 1024, Wo 4096 transpose blocks (32x32 tiles).
// ---------------------------------------------------------------------------
__global__ __launch_bounds__(256) void prep(
    const float* __restrict__ x, ushort* __restrict__ xb,
    const float* __restrict__ Wq, const float* __restrict__ Wk,
    const float* __restrict__ Wv, const float* __restrict__ Wo,
    ushort* __restrict__ wqkvT, ushort* __restrict__ woT) {
  __shared__ float tile[32][33];
  const int bid = blockIdx.x;
  const int tid = threadIdx.x;
  if (bid < 8192) {  // x convert: 4096*2048 elems, 4/thread
    int i = (bid * 256 + tid) * 4;
    float4 v = *(const float4*)&x[i];
    ushort4 o;
    o.x = f2bf(v.x); o.y = f2bf(v.y); o.z = f2bf(v.z); o.w = f2bf(v.w);
    *(ushort4*)&xb[i] = o;
    return;
  }
  const float* in;
  ushort* out;
  int N, lid;
  if (bid < 12288)      { in = Wq; out = wqkvT;                        N = 2048; lid = bid - 8192; }
  else if (bid < 13312) { in = Wk; out = wqkvT + (size_t)2048 * 2048;  N = 512;  lid = bid - 12288; }
  else if (bid < 14336) { in = Wv; out = wqkvT + (size_t)2560 * 2048;  N = 512;  lid = bid - 13312; }
  else                  { in = Wo; out = woT;                          N = 2048; lid = bid - 14336; }
  const int K = 2048;
  const int nb = N / 32;
  const int n0 = (lid % nb) * 32, k0 = (lid / nb) * 32;
  const int r = tid >> 3, c4 = (tid & 7) << 2;
  float4 v = *(const float4*)&in[(size_t)(k0 + r) * N + n0 + c4];
  tile[r][c4 + 0] = v.x; tile[r][c4 + 1] = v.y;
  tile[r][c4 + 2] = v.z; tile[r][c4 + 3] = v.w;
  __syncthreads();
  ushort4 o;
  o.x = f2bf(tile[c4 + 0][r]); o.y = f2bf(tile[c4 + 1][r]);
  o.z = f2bf(tile[c4 + 2][r]); o.w = f2bf(tile[c4 + 3][r]);
  *(ushort4*)&out[(size_t)(n0 + r) * K + k0 + c4] = o;
}

// ---------------------------------------------------------------------------
// bf16 GEMM C[M,N] = A[M,K] * Bt[N,K]^T. 128x128 tile, BK=32, 4 waves (2x2),
// global_load_lds staging, XOR-swizzled LDS. SIMPLE epilogue only (acc must
// stay in AGPRs — round-6's fused epilogue caused main-loop spills: 2.6 GB
// of scratch writes, 762 us. Do not fuse complex math into this epilogue.)
// ---------------------------------------------------------------------------
template <typename OutT>
__global__ __launch_bounds__(256) void gemm_bt(const ushort* __restrict__ A,
                                               const ushort* __restrict__ Bt,
                                               OutT* __restrict__ C,
                                               int M, int N, int K) {
  __shared__ __align__(16) ushort As[128 * 32];
  __shared__ __align__(16) ushort Bs[128 * 32];
  const int tid = threadIdx.x;
  const int w = tid >> 6, l = tid & 63;
  const int wr = w >> 1, wc = w & 1;
  const int quad = l >> 4, l15 = l & 15;
  const int bm = blockIdx.y * 128, bn = blockIdx.x * 128;

  f32x4 acc[4][4];
#pragma unroll
  for (int mi = 0; mi < 4; ++mi)
#pragma unroll
    for (int ni = 0; ni < 4; ++ni)
#pragma unroll
      for (int r = 0; r < 4; ++r) acc[mi][ni][r] = 0.f;

  for (int k0 = 0; k0 < K; k0 += 32) {
    __syncthreads();
#pragma unroll
    for (int j = 0; j < 2; ++j) {
      int r0 = w * 32 + j * 16;
      int row = r0 + (l >> 2);
      int gc = (l & 3) ^ ((row >> 1) & 3);
      ld16(&As[r0 * 32], &A[(size_t)(bm + row) * K + k0 + gc * 8]);
      ld16(&Bs[r0 * 32], &Bt[(size_t)(bn + row) * K + k0 + gc * 8]);
    }
    __syncthreads();
    short8 af[4], bf[4];
#pragma unroll
    for (int mi = 0; mi < 4; ++mi) {
      int m = wr * 64 + mi * 16 + l15;
      af[mi] = *(const short8*)&As[m * 32 + (quad ^ ((m >> 1) & 3)) * 8];
    }
#pragma unroll
    for (int ni = 0; ni < 4; ++ni) {
      int n = wc * 64 + ni * 16 + l15;
      bf[ni] = *(const short8*)&Bs[n * 32 + (quad ^ ((n >> 1) & 3)) * 8];
    }
#pragma unroll
    for (int mi = 0; mi < 4; ++mi)
#pragma unroll
      for (int ni = 0; ni < 4; ++ni)
        acc[mi][ni] = __builtin_amdgcn_mfma_f32_16x16x32_bf16(af[mi], bf[ni], acc[mi][ni], 0, 0, 0);
  }
  // epilogue: C/D layout col=lane&15, row=quad*4+reg
#pragma unroll
  for (int mi = 0; mi < 4; ++mi)
#pragma unroll
    for (int ni = 0; ni < 4; ++ni)
#pragma unroll
      for (int r = 0; r < 4; ++r) {
        int grow = bm + wr * 64 + mi * 16 + quad * 4 + r;
        int gcol = bn + wc * 64 + ni * 16 + l15;
        if constexpr (__is_same(OutT, ushort))
          C[(size_t)grow * N + gcol] = f2bf(acc[mi][ni][r]);
        else
          C[(size_t)grow * N + gcol] = acc[mi][ni][r];
      }
}

// ---------------------------------------------------------------------------
// RoPE in-place on bf16 K columns of qkv [4096][3072] (cols 2048..2559).
// Q rope is fused into attn.
// ---------------------------------------------------------------------------
__global__ __launch_bounds__(256) void rope_k_bf16(ushort* __restrict__ qkv) {
  int idx = blockIdx.x * 256 + threadIdx.x;
  const int PAIRS_PER_ROW = 256;  // NKV*64
  if (idx >= BATCH * T_SEQ * PAIRS_PER_ROW) return;
  int row = idx >> 8;
  int kp = idx & 255;
  int t = row & (T_SEQ - 1);
  int i = kp & 63;
  ushort* ptr = qkv + (size_t)row * 3072 + 2048 + 2 * kp;
  float inv = expf((float)i * -0.14391156831212788f);  // ln(10000)/64
  float ang = (float)t * inv;
  float sn, cs;
  sincosf(ang, &sn, &cs);
  float x1 = bf2f(ptr[0]), x2 = bf2f(ptr[1]);
  ptr[0] = f2bf(x1 * cs - x2 * sn);
  ptr[1] = f2bf(x1 * sn + x2 * cs);
}

// ---------------------------------------------------------------------------
// v columns of qkv [4096][3072] (cols 2560..3071) -> vT [512][4096] bf16.
// grid (4096/32, 512/32).
// ---------------------------------------------------------------------------
__global__ __launch_bounds__(256) void transpose_v(const ushort* __restrict__ qkv,
                                                   ushort* __restrict__ vT) {
  __shared__ ushort tile[32][34];
  int m0 = blockIdx.x * 32, d0 = blockIdx.y * 32;
  int r = threadIdx.x >> 3, c4 = (threadIdx.x & 7) << 2;
  ushort4 v = *(const ushort4*)&qkv[(size_t)(m0 + r) * 3072 + 2560 + d0 + c4];
  tile[r][c4 + 0] = v.x; tile[r][c4 + 1] = v.y;
  tile[r][c4 + 2] = v.z; tile[r][c4 + 3] = v.w;
  __syncthreads();
  ushort4 o;
  o.x = tile[c4 + 0][r]; o.y = tile[c4 + 1][r];
  o.z = tile[c4 + 2][r]; o.w = tile[c4 + 3][r];
  *(ushort4*)&vT[(size_t)(d0 + r) * 4096 + m0 + c4] = o;
}

// ---------------------------------------------------------------------------
// MFMA flash attention v5 (unchanged from round 6 — it worked).
// grid (32, NKV, B), 512 thr = 8 waves. Block covers 4 q-heads x 32 q-rows
// sharing K/V staging; two complementary q-tiles (63-bx, bx) -> exactly 33
// k-iters/block, 256-block balanced grid. No-max softmax, double-buffered
// K/V, SC folded into Q frags, truncated P converts. LDS 80KB.
// ---------------------------------------------------------------------------
__global__ __launch_bounds__(512, 2) void attn_mfma(const ushort* __restrict__ qkv,
                                                    const ushort* __restrict__ vT,
                                                    ushort* __restrict__ ao) {
  __shared__ __align__(16) ushort Ks[2][64 * 128];
  __shared__ __align__(16) ushort Vt[2][128 * 64];
  __shared__ __align__(16) ushort Ps[8][16 * 64];
  const int tid = threadIdx.x;
  const int w = tid >> 6, l = tid & 63;
  const int quad = l >> 4, l15 = l & 15;
  const int hw = w >> 1, sub = w & 1;
  const int kvh = blockIdx.y, b = blockIdx.z;
  const int h = kvh * 4 + hw;
  const size_t krow0 = (size_t)b * T_SEQ;
  const float SC = 0.12751744595764253f;  // (1/sqrt(128)) * log2(e)

  ushort* pw = Ps[w];
  const int within = l & 7;
  const int colbase = l15 >> 3;  // 0 or 1

  auto stage = [&](int kt, int bufi) {
    const int kt0 = kt << 6;
    ushort* kb = Ks[bufi];
    ushort* vb = Vt[bufi];
#pragma unroll
    for (int j = 0; j < 2; ++j) {  // K tile 64x128
      int r0 = w * 8 + j * 4;
      int row = r0 + (l >> 4);
      int gc = (l & 15) ^ ((row >> 1) & 7);
      ld16(&kb[r0 * 128], &qkv[(krow0 + kt0 + row) * 3072 + 2048 + kvh * 128 + gc * 8]);
    }
#pragma unroll
    for (int j = 0; j < 2; ++j) {  // V^T tile 128x64
      int r0 = w * 16 + j * 8;
      int row = r0 + (l >> 3);
      int gc = (l & 7) ^ (row & 7);
      ld16(&vb[r0 * 64], &vT[(size_t)(kvh * 128 + row) * 4096 + krow0 + kt0 + gc * 8]);
    }
  };

#pragma unroll 1
  for (int ph = 0; ph < 2; ++ph) {
    const int qt = ph ? (int)blockIdx.x : 63 - (int)blockIdx.x;
    const int qt0 = qt << 5;
    const size_t qrow0 = krow0 + qt0;

    // Q fragments in registers; RoPE + SC folded in.
    const int t_pos = qt0 + sub * 16 + l15;
    short8 qf[4];
#pragma unroll
    for (int kc = 0; kc < 4; ++kc) {
      short8 raw = *(const short8*)&qkv[(qrow0 + sub * 16 + l15) * 3072 + h * 128 + kc * 32 + quad * 8];
#pragma unroll
      for (int u = 0; u < 4; ++u) {
        int i_idx = kc * 16 + quad * 4 + u;
        float inv = expf((float)i_idx * -0.14391156831212788f);  // ln(10000)/64
        float sn, cs;
        sincosf((float)t_pos * inv, &sn, &cs);
        cs *= SC; sn *= SC;
        float x1 = bf2f((ushort)raw[2 * u]);
        float x2 = bf2f((ushort)raw[2 * u + 1]);
        qf[kc][2 * u]     = (short)f2bf(x1 * cs - x2 * sn);
        qf[kc][2 * u + 1] = (short)f2bf(x1 * sn + x2 * cs);
      }
    }

    f32x4 oacc[8];
#pragma unroll
    for (int i = 0; i < 8; ++i)
#pragma unroll
      for (int r = 0; r < 4; ++r) oacc[i][r] = 0.f;
    float lpart[4] = {0.f, 0.f, 0.f, 0.f};

    const int nkt = (qt >> 1) + 1;
    __syncthreads();  // prior phase's LDS reads complete before re-priming
    stage(0, 0);
    for (int kt = 0; kt < nkt; ++kt) {
      __syncthreads();  // (vmcnt drain) stage(kt) landed; prior buffer free
      if (kt + 1 < nkt) stage(kt + 1, (kt + 1) & 1);
      const ushort* kb = Ks[kt & 1];
      const ushort* vb = Vt[kt & 1];

      // S = Q K^T (wave rows sub*16.., cols 0..63); already scaled by SC
      f32x4 sacc[4];
#pragma unroll
      for (int ni = 0; ni < 4; ++ni)
#pragma unroll
        for (int r = 0; r < 4; ++r) sacc[ni][r] = 0.f;
#pragma unroll
      for (int kc = 0; kc < 4; ++kc) {
#pragma unroll
        for (int ni = 0; ni < 4; ++ni) {
          int n = ni * 16 + l15;
          short8 bfr = *(const short8*)&kb[n * 128 + ((kc * 4 + quad) ^ ((n >> 1) & 7)) * 8];
          sacc[ni] = __builtin_amdgcn_mfma_f32_16x16x32_bf16(qf[kc], bfr, sacc[ni], 0, 0, 0);
        }
      }

      // p = exp2(s); stream to LDS (truncated bf16); accumulate partial l.
      const int kt0 = kt << 6;
      if (kt == nkt - 1) {  // diagonal tile: causal mask
        const int rowg = qt0 + sub * 16 + quad * 4;
#pragma unroll
        for (int ni = 0; ni < 4; ++ni) {
          const int colid = kt0 + ni * 16 + l15;
#pragma unroll
          for (int r = 0; r < 4; ++r) {
            float s = (colid > rowg + r) ? -1e30f : sacc[ni][r];
            float pv = __builtin_amdgcn_exp2f(s);
            lpart[r] += pv;
            int prow = quad * 4 + r;
            pw[prow * 64 + (((ni * 2 + colbase) ^ (prow & 7)) << 3) + within] = f2bf_trunc(pv);
          }
        }
      } else {
#pragma unroll
        for (int ni = 0; ni < 4; ++ni)
#pragma unroll
          for (int r = 0; r < 4; ++r) {
            float pv = __builtin_amdgcn_exp2f(sacc[ni][r]);
            lpart[r] += pv;
            int prow = quad * 4 + r;
            pw[prow * 64 + (((ni * 2 + colbase) ^ (prow & 7)) << 3) + within] = f2bf_trunc(pv);
          }
      }

      // O += P V  (A = Ps rows m=l&15, B = Vt rows d)
#pragma unroll
      for (int kc = 0; kc < 2; ++kc) {
        short8 a = *(const short8*)&pw[l15 * 64 + ((kc * 4 + quad) ^ (l15 & 7)) * 8];
#pragma unroll
        for (int ni2 = 0; ni2 < 8; ++ni2) {
          int d = ni2 * 16 + l15;
          short8 bfr = *(const short8*)&vb[d * 64 + ((kc * 4 + quad) ^ (d & 7)) * 8];
          oacc[ni2] = __builtin_amdgcn_mfma_f32_16x16x32_bf16(a, bfr, oacc[ni2], 0, 0, 0);
        }
      }
    }

    // phase epilogue: one butterfly reduce of l per row, normalize + store
#pragma unroll
    for (int r = 0; r < 4; ++r) {
      float lv = lpart[r];
      lv += __shfl_xor(lv, 1);
      lv += __shfl_xor(lv, 2);
      lv += __shfl_xor(lv, 4);
      lv += __shfl_xor(lv, 8);
      float inv = 1.f / lv;
      size_t grow = qrow0 + sub * 16 + quad * 4 + r;
#pragma unroll
      for (int ni2 = 0; ni2 < 8; ++ni2)
        ao[grow * 2048 + h * 128 + ni2 * 16 + l15] = f2bf(oacc[ni2][r] * inv);
    }
  }
}

// ---------------------------------------------------------------------------
extern "C" void kernel_launch(void* const* d_in, const int* in_sizes, int n_in,
                              void* d_out, int out_size, void* d_ws, size_t ws_size,
                              hipStream_t stream) {
  const float* x  = (const float*)d_in[0];
  const float* Wq = (const float*)d_in[1];
  const float* Wk = (const float*)d_in[2];
  const float* Wv = (const float*)d_in[3];
  const float* Wo = (const float*)d_in[4];
  float* y = (float*)d_out;

  const int M = BATCH * T_SEQ;  // 4096
  ushort* xb    = (ushort*)d_ws;                    // 4096*2048  (16 MB)
  ushort* wqkvT = xb + (size_t)M * 2048;            // 3072*2048  (12 MB)
  ushort* woT   = wqkvT + (size_t)3072 * 2048;      // 2048*2048  ( 8 MB)
  ushort* qkv   = woT + (size_t)2048 * 2048;        // 4096*3072  (24 MB)
  ushort* vTb   = qkv + (size_t)M * 3072;           // 512*4096   ( 4 MB)
  ushort* aob   = vTb + (size_t)512 * 4096;         // 4096*2048  (16 MB)

  prep<<<18432, 256, 0, stream>>>(x, xb, Wq, Wk, Wv, Wo, wqkvT, woT);

  gemm_bt<ushort><<<dim3(3072 / 128, M / 128), 256, 0, stream>>>(
      xb, wqkvT, qkv, M, 3072, 2048);

  rope_k_bf16<<<(M * 256 + 255) / 256, 256, 0, stream>>>(qkv);
  transpose_v<<<dim3(M / 32, 512 / 32), 256, 0, stream>>>(qkv, vTb);

  attn_mfma<<<dim3(32, NKV, BATCH), 512, 0, stream>>>(qkv, vTb, aob);

  gemm_bt<float><<<dim3(2048 / 128, M / 128), 256, 0, stream>>>(
      aob, woT, y, M, 2048, 2048);
}